// Round 4
// baseline (528.159 us; speedup 1.0000x reference)
//
#include <hip/hip_runtime.h>
#include <hip/hip_fp16.h>
#include <math.h>

#define NRAYS 32768
#define NPTS  200
#define RPB   16                 // rays per block
#define PPB   (RPB * NPTS)       // 3200 points per block
#define DENSE_U32 315496         // u32 words in dense pair region
#define W_U32  1101928           // total u32 words in rebuilt table

constexpr unsigned PRIME1 = 2654435761u;
constexpr unsigned PRIME2 = 805459861u;
constexpr unsigned HMASK  = (1u << 19) - 1u;

static __device__ constexpr float    k_scales[6]  = {15.f, 31.f, 63.f, 127.f, 255.f, 511.f};
static __device__ constexpr unsigned k_strides[6] = {17u, 33u, 65u, 129u, 257u, 513u};
static __device__ constexpr unsigned k_offs[6]    = {0u, 4920u, 40864u, 315496u, 839784u, 1364072u};
// u32-word base of hashed level l (l>=3) in rebuilt table
static __device__ constexpr unsigned k_h32[3] = {315496u, 577640u, 839784u};

__device__ __forceinline__ float2 up2(unsigned w) {
    __half2 h = *reinterpret_cast<__half2*>(&w);
    return __half22float2(h);
}
__device__ __forceinline__ float h2f_sel(unsigned pack, unsigned hi) {
    union { unsigned short us; __half h; } cv;
    cv.us = (unsigned short)(pack >> (hi << 4));
    return __half2float(cv.h);
}

// --- K0: rebuild table: dense levels as (T[i],T[i+1]) fp16 pairs; hashed levels packed fp16 ---
extern "C" __global__ void __launch_bounds__(256)
k_build(const float* __restrict__ T, unsigned* __restrict__ W) {
    int i = blockIdx.x * 256 + threadIdx.x;
    if (i >= W_U32) return;
    float a, b;
    if (i < DENSE_U32) { a = T[i]; b = T[i + 1]; }
    else { int r = 2 * i - DENSE_U32; a = T[r]; b = T[r + 1]; }
    union { __half h; unsigned short u; } ca, cb;
    ca.h = __float2half_rn(a);
    cb.h = __float2half_rn(b);
    W[i] = (unsigned)ca.u | ((unsigned)cb.u << 16);
}

// --- K0b: transpose MLP weights into workspace: wT[k*64+n] = w[n*K+k] ---
extern "C" __global__ void __launch_bounds__(256)
k_wt(const float* __restrict__ w1, const float* __restrict__ w2,
     const float* __restrict__ w3, float* __restrict__ wt) {
    int i = blockIdx.x * 256 + threadIdx.x;   // 0..9919
    if (i < 1728) {                            // w1T: 27x64
        const int k = i >> 6, n = i & 63;
        wt[i] = w1[n * 27 + k];
    } else if (i < 1728 + 4096) {              // w2T
        const int j = i - 1728, k = j >> 6, n = j & 63;
        wt[i] = w2[n * 64 + k];
    } else if (i < 1728 + 8192) {              // w3T
        const int j = i - 5824, k = j >> 6, n = j & 63;
        wt[i] = w3[n * 64 + k];
    }
}

// fp32 corner indices (RGB encode phase only — reads original fp32 table)
__device__ __forceinline__ void corner_indices(int l, float qx, float qy, float qz,
                                               unsigned idx[8],
                                               float& fx, float& fy, float& fz)
{
    const float scale = k_scales[l];
    float px = qx * scale + 0.5f;
    float py = qy * scale + 0.5f;
    float pz = qz * scale + 0.5f;
    float gx = floorf(px), gy = floorf(py), gz = floorf(pz);
    fx = px - gx; fy = py - gy; fz = pz - gz;
    unsigned ix = (unsigned)gx, iy = (unsigned)gy, iz = (unsigned)gz;
    const unsigned off = k_offs[l];
    if (l < 3) {
        const unsigned S  = k_strides[l];
        const unsigned S2 = S * S;
        const unsigned base = off + ix + iy * S + iz * S2;
        idx[0] = base;          idx[1] = base + 1u;
        idx[2] = base + S;      idx[3] = base + S + 1u;
        idx[4] = base + S2;     idx[5] = base + S2 + 1u;
        idx[6] = base + S2 + S; idx[7] = base + S2 + S + 1u;
    } else {
        const unsigned x0 = ix, x1 = ix + 1u;
        const unsigned hy0 = iy * PRIME1, hy1 = hy0 + PRIME1;
        const unsigned hz0 = iz * PRIME2, hz1 = hz0 + PRIME2;
        idx[0] = off + ((x0 ^ hy0 ^ hz0) & HMASK);
        idx[1] = off + ((x1 ^ hy0 ^ hz0) & HMASK);
        idx[2] = off + ((x0 ^ hy1 ^ hz0) & HMASK);
        idx[3] = off + ((x1 ^ hy1 ^ hz0) & HMASK);
        idx[4] = off + ((x0 ^ hy0 ^ hz1) & HMASK);
        idx[5] = off + ((x1 ^ hy0 ^ hz1) & HMASK);
        idx[6] = off + ((x0 ^ hy1 ^ hz1) & HMASK);
        idx[7] = off + ((x1 ^ hy1 ^ hz1) & HMASK);
    }
}

extern "C" __global__ void __launch_bounds__(256, 6)
fused_nerf(const float4* __restrict__ x4,
           const unsigned* __restrict__ W,     // rebuilt fp16 label table
           const float*   __restrict__ wt,     // [w1T 1728 | w2T 4096 | w3T 4096]
           const float4*  __restrict__ tr,
           const float*   __restrict__ wl,
           const float*   __restrict__ bl,
           const float*   __restrict__ b1,
           const float*   __restrict__ b2,
           const float*   __restrict__ b3,
           const float*   __restrict__ w4, const float* __restrict__ b4,
           float* __restrict__ o_hits,
           float* __restrict__ o_sig,
           float* __restrict__ o_idx,
           float* __restrict__ o_rgb)
{
    const int tid = threadIdx.x;
    const int ray0 = blockIdx.x * RPB;

    __shared__ float s_sig[PPB];       // 12800 B
    __shared__ float s_geom[RPB * 8];  // 512 B
    __shared__ float s_h0[RPB * 28];   // 1792 B
    __shared__ float s_hA[RPB * 64];   // 4096 B
    __shared__ float s_hB[RPB * 64];   // 4096 B
    __shared__ int   s_fi[RPB];        // 64 B

    // ---- phase 0: per-ray geometry ----
    if (tid < RPB) {
        const float4 ang = x4[ray0 + tid];
        float st1, ct1, sp1, cp1, st2, ct2, sp2, cp2;
        sincosf(ang.x, &st1, &ct1);
        sincosf(ang.y, &sp1, &cp1);
        sincosf(ang.z, &st2, &ct2);
        sincosf(ang.w, &sp2, &cp2);
        const float p1x = st1 * cp1, p1y = st1 * sp1, p1z = ct1;
        const float p2x = st2 * cp2, p2y = st2 * sp2, p2z = ct2;
        const float dx = p2x - p1x, dy = p2y - p1y, dz = p2z - p1z;
        float len = sqrtf(dx * dx + dy * dy + dz * dz);
        len = fminf(fmaxf(len, 1e-6f), 1e6f);
        float* g = &s_geom[tid * 8];
        g[0] = p1x; g[1] = p1y; g[2] = p1z; g[3] = len;
        g[4] = dx;  g[5] = dy;  g[6] = dz;  g[7] = 0.f;
    }
    __syncthreads();

    // ---- phase 1: label encode + sigmoid for 3200 points (branchless gathers) ----
    const size_t sig_base = (size_t)blockIdx.x * PPB;
    auto process = [&](int p) {
        const int r = (p * 5243) >> 20;      // p / 200 for p < 3200
        const int t = p - r * 200;
        const float* g = &s_geom[r * 8];
        const float tt = (float)t * (1.0f / 199.0f);
        const float qx = ((g[0] + g[4] * tt) + 1.0f) * 0.5f;
        const float qy = ((g[1] + g[5] * tt) + 1.0f) * 0.5f;
        const float qz = ((g[2] + g[6] * tt) + 1.0f) * 0.5f;

        float feat[6];
        #pragma unroll
        for (int l = 0; l < 6; ++l) {
            const float scale = k_scales[l];
            float px = qx * scale + 0.5f;
            float py = qy * scale + 0.5f;
            float pz = qz * scale + 0.5f;
            float gx = floorf(px), gy = floorf(py), gz = floorf(pz);
            const float fx = px - gx, fy = py - gy, fz = pz - gz;
            const unsigned ix = (unsigned)gx, iy = (unsigned)gy, iz = (unsigned)gz;
            const float wx0 = 1.0f - fx, wx1 = fx;
            const float wyz[4] = { (1.0f - fy) * (1.0f - fz), fy * (1.0f - fz),
                                   (1.0f - fy) * fz,          fy * fz };
            float acc = 0.0f;
            if (l < 3) {
                const unsigned S  = k_strides[l];
                const unsigned S2 = S * S;
                const unsigned base = k_offs[l] + ix + iy * S + iz * S2;
                const float2 c0 = up2(W[base]);
                const float2 c1 = up2(W[base + S]);
                const float2 c2 = up2(W[base + S2]);
                const float2 c3 = up2(W[base + S2 + S]);
                acc = fmaf(wx0 * wyz[0], c0.x, acc);
                acc = fmaf(wx1 * wyz[0], c0.y, acc);
                acc = fmaf(wx0 * wyz[1], c1.x, acc);
                acc = fmaf(wx1 * wyz[1], c1.y, acc);
                acc = fmaf(wx0 * wyz[2], c2.x, acc);
                acc = fmaf(wx1 * wyz[2], c2.y, acc);
                acc = fmaf(wx0 * wyz[3], c3.x, acc);
                acc = fmaf(wx1 * wyz[3], c3.y, acc);
            } else {
                const unsigned h32 = k_h32[l - 3];
                const unsigned hy0 = iy * PRIME1, hy1 = hy0 + PRIME1;
                const unsigned hz0 = iz * PRIME2, hz1 = hz0 + PRIME2;
                const unsigned x1 = ix + 1u;
                const unsigned e[4] = { hy0 ^ hz0, hy1 ^ hz0, hy0 ^ hz1, hy1 ^ hz1 };
                #pragma unroll
                for (int j = 0; j < 4; ++j) {
                    const unsigned a = (ix ^ e[j]) & HMASK;
                    const unsigned b = (x1 ^ e[j]) & HMASK;
                    const unsigned pa = W[h32 + (a >> 1)];
                    const unsigned pb = W[h32 + (b >> 1)];
                    acc = fmaf(wx0 * wyz[j], h2f_sel(pa, a & 1u), acc);
                    acc = fmaf(wx1 * wyz[j], h2f_sel(pb, b & 1u), acc);
                }
            }
            feat[l] = acc;
        }
        float z = bl[0];
        #pragma unroll
        for (int l = 0; l < 6; ++l) z = fmaf(feat[l], wl[l], z);
        const float out = 1.0f / (1.0f + __expf(-z));
        o_sig[sig_base + p] = out;
        s_sig[p] = out;
    };

    #pragma unroll 1
    for (int k = 0; k < 6; ++k) {
        const int p0 = tid + k * 512;
        process(p0);          // two independent points in flight
        process(p0 + 256);
    }
    if (tid < 128) process(tid + 3072);
    __syncthreads();

    // ---- phase 2: per-ray max + first-hit (16 threads per ray) ----
    {
        const int g = tid >> 4, l = tid & 15;
        float vmax = -1.0f;
        int fh = 0x7fff;
        #pragma unroll
        for (int j = 0; j < 13; ++j) {
            const int t = l + j * 16;
            if (t < 200) {
                const float v = s_sig[g * 200 + t];
                vmax = fmaxf(vmax, v);
                if (v > 0.5f) fh = min(fh, t);
            }
        }
        #pragma unroll
        for (int m = 8; m >= 1; m >>= 1) {
            vmax = fmaxf(vmax, __shfl_xor(vmax, m, 64));
            fh = min(fh, __shfl_xor(fh, m, 64));
        }
        if (l == 0) {
            o_hits[ray0 + g] = vmax;
            const int fi = (fh == 0x7fff) ? 0 : fh;
            s_fi[g] = fi;
            o_idx[ray0 + g] = (float)fi;
        }
    }
    __syncthreads();

    // ---- phase 3: dirs + RGB encode at hit points ----
    if (tid < RPB) {
        const float* g = &s_geom[tid * 8];
        const float inv = 1.0f / g[3];
        s_h0[tid * 28 + 0] = g[4] * inv;
        s_h0[tid * 28 + 1] = g[5] * inv;
        s_h0[tid * 28 + 2] = g[6] * inv;
        s_h0[tid * 28 + 27] = 0.f;
    }
    if (tid < RPB * 6) {
        const int r = (tid * 171) >> 10;   // tid / 6
        const int l = tid - r * 6;
        const float* g = &s_geom[r * 8];
        const float t  = (float)s_fi[r] * (1.0f / 199.0f);
        const float qx = ((g[0] + g[4] * t) + 1.0f) * 0.5f;
        const float qy = ((g[1] + g[5] * t) + 1.0f) * 0.5f;
        const float qz = ((g[2] + g[6] * t) + 1.0f) * 0.5f;
        unsigned idx[8];
        float fx, fy, fz;
        corner_indices(l, qx, qy, qz, idx, fx, fy, fz);
        const float ex = 1.0f - fx, ey = 1.0f - fy, ez = 1.0f - fz;
        const float w[8] = { ex * ey * ez, fx * ey * ez, ex * fy * ez, fx * fy * ez,
                             ex * ey * fz, fx * ey * fz, ex * fy * fz, fx * fy * fz };
        float ax = 0.f, ay = 0.f, az = 0.f, aw = 0.f;
        #pragma unroll
        for (int c = 0; c < 8; ++c) {
            float4 v = tr[idx[c]];
            ax = fmaf(w[c], v.x, ax);
            ay = fmaf(w[c], v.y, ay);
            az = fmaf(w[c], v.z, az);
            aw = fmaf(w[c], v.w, aw);
        }
        float* h = &s_h0[r * 28 + 3 + l * 4];
        h[0] = ax; h[1] = ay; h[2] = az; h[3] = aw;
    }
    __syncthreads();

    // ---- phase 4: MLP (weights from global, transposed & L2-resident) ----
    const int n = tid & 63;
    const int wv = tid >> 6;
    const float* w1T = wt;
    const float* w2T = wt + 1728;
    const float* w3T = wt + 5824;
    {
        float a0 = b1[n], a1 = a0, a2 = a0, a3 = a0;
        #pragma unroll
        for (int k = 0; k < 27; ++k) {
            const float w = w1T[k * 64 + n];
            a0 = fmaf(s_h0[(wv     ) * 28 + k], w, a0);
            a1 = fmaf(s_h0[(wv +  4) * 28 + k], w, a1);
            a2 = fmaf(s_h0[(wv +  8) * 28 + k], w, a2);
            a3 = fmaf(s_h0[(wv + 12) * 28 + k], w, a3);
        }
        s_hA[(wv     ) * 64 + n] = fmaxf(a0, 0.0f);
        s_hA[(wv +  4) * 64 + n] = fmaxf(a1, 0.0f);
        s_hA[(wv +  8) * 64 + n] = fmaxf(a2, 0.0f);
        s_hA[(wv + 12) * 64 + n] = fmaxf(a3, 0.0f);
    }
    __syncthreads();
    {
        float a0 = b2[n], a1 = a0, a2 = a0, a3 = a0;
        #pragma unroll
        for (int k = 0; k < 64; ++k) {
            const float w = w2T[k * 64 + n];
            a0 = fmaf(s_hA[(wv     ) * 64 + k], w, a0);
            a1 = fmaf(s_hA[(wv +  4) * 64 + k], w, a1);
            a2 = fmaf(s_hA[(wv +  8) * 64 + k], w, a2);
            a3 = fmaf(s_hA[(wv + 12) * 64 + k], w, a3);
        }
        s_hB[(wv     ) * 64 + n] = fmaxf(a0, 0.0f);
        s_hB[(wv +  4) * 64 + n] = fmaxf(a1, 0.0f);
        s_hB[(wv +  8) * 64 + n] = fmaxf(a2, 0.0f);
        s_hB[(wv + 12) * 64 + n] = fmaxf(a3, 0.0f);
    }
    __syncthreads();
    {
        float a0 = b3[n], a1 = a0, a2 = a0, a3 = a0;
        #pragma unroll
        for (int k = 0; k < 64; ++k) {
            const float w = w3T[k * 64 + n];
            a0 = fmaf(s_hB[(wv     ) * 64 + k], w, a0);
            a1 = fmaf(s_hB[(wv +  4) * 64 + k], w, a1);
            a2 = fmaf(s_hB[(wv +  8) * 64 + k], w, a2);
            a3 = fmaf(s_hB[(wv + 12) * 64 + k], w, a3);
        }
        s_hA[(wv     ) * 64 + n] = fmaxf(a0, 0.0f);
        s_hA[(wv +  4) * 64 + n] = fmaxf(a1, 0.0f);
        s_hA[(wv +  8) * 64 + n] = fmaxf(a2, 0.0f);
        s_hA[(wv + 12) * 64 + n] = fmaxf(a3, 0.0f);
    }
    __syncthreads();
    if (tid < RPB * 3) {
        const int r = (tid * 86) >> 8;     // tid / 3
        const int c = tid - r * 3;
        float acc = b4[c];
        #pragma unroll
        for (int k = 0; k < 64; ++k) acc = fmaf(s_hA[r * 64 + k], w4[c * 64 + k], acc);
        o_rgb[(ray0 + r) * 3 + c] = acc;
    }
}

extern "C" void kernel_launch(void* const* d_in, const int* in_sizes, int n_in,
                              void* d_out, int out_size, void* d_ws, size_t ws_size,
                              hipStream_t stream) {
    const float* x  = (const float*)d_in[0];
    const float* tl = (const float*)d_in[1];
    const float* tr = (const float*)d_in[2];
    const float* wl = (const float*)d_in[3];
    const float* bl = (const float*)d_in[4];
    const float* w1 = (const float*)d_in[5];
    const float* b1 = (const float*)d_in[6];
    const float* w2 = (const float*)d_in[7];
    const float* b2 = (const float*)d_in[8];
    const float* w3 = (const float*)d_in[9];
    const float* b3 = (const float*)d_in[10];
    const float* w4 = (const float*)d_in[11];
    const float* b4 = (const float*)d_in[12];

    float* o      = (float*)d_out;
    float* o_hits = o;
    float* o_sig  = o + NRAYS;
    float* o_idx  = o_sig + (size_t)NRAYS * NPTS;
    float* o_rgb  = o_idx + NRAYS;

    // ws layout: [ u32 table: 4,407,712 B | pad to 4,407,808 | wT: 9920 floats ]
    unsigned* W  = (unsigned*)d_ws;
    float*    wt = (float*)((char*)d_ws + 4407808);

    k_build<<<dim3((W_U32 + 255) / 256), dim3(256), 0, stream>>>(tl, W);
    k_wt<<<dim3((9920 + 255) / 256), dim3(256), 0, stream>>>(w1, w2, w3, wt);
    fused_nerf<<<dim3(NRAYS / RPB), dim3(256), 0, stream>>>(
        (const float4*)x, W, wt, (const float4*)tr, wl, bl,
        b1, b2, b3, w4, b4,
        o_hits, o_sig, o_idx, o_rgb);
}

// Round 5
// 388.284 us; speedup vs baseline: 1.3602x; 1.3602x over previous
//
#include <hip/hip_runtime.h>
#include <hip/hip_fp16.h>
#include <math.h>

#define NRAYS 32768
#define NPTS  200
#define RPB   8                  // rays per block
#define PPB   (RPB * NPTS)       // 1600 points per block
#define DENSE_U32 315496         // u32 words in dense pair region
#define W_U32  1101928           // total u32 words in rebuilt table

constexpr unsigned PRIME1 = 2654435761u;
constexpr unsigned PRIME2 = 805459861u;
constexpr unsigned HMASK  = (1u << 19) - 1u;

static __device__ constexpr float    k_scales[6]  = {15.f, 31.f, 63.f, 127.f, 255.f, 511.f};
static __device__ constexpr unsigned k_strides[6] = {17u, 33u, 65u, 129u, 257u, 513u};
static __device__ constexpr unsigned k_offs[6]    = {0u, 4920u, 40864u, 315496u, 839784u, 1364072u};
// u32-word base of hashed level l (l>=3) in rebuilt table
static __device__ constexpr unsigned k_h32[3] = {315496u, 577640u, 839784u};

__device__ __forceinline__ float2 up2(unsigned w) {
    __half2 h = *reinterpret_cast<__half2*>(&w);
    return __half22float2(h);
}
__device__ __forceinline__ float h2f_sel(unsigned pack, unsigned hi) {
    union { unsigned short us; __half h; } cv;
    cv.us = (unsigned short)(pack >> (hi << 4));
    return __half2float(cv.h);
}

// --- K0: rebuild table: dense levels as (T[i],T[i+1]) fp16 pairs; hashed levels packed fp16 ---
extern "C" __global__ void __launch_bounds__(256)
k_build(const float* __restrict__ T, unsigned* __restrict__ W) {
    int i = blockIdx.x * 256 + threadIdx.x;
    if (i >= W_U32) return;
    float a, b;
    if (i < DENSE_U32) { a = T[i]; b = T[i + 1]; }
    else { int r = 2 * i - DENSE_U32; a = T[r]; b = T[r + 1]; }
    union { __half h; unsigned short u; } ca, cb;
    ca.h = __float2half_rn(a);
    cb.h = __float2half_rn(b);
    W[i] = (unsigned)ca.u | ((unsigned)cb.u << 16);
}

// --- K0b: transpose MLP weights into workspace: wT[k*64+n] = w[n*K+k] ---
extern "C" __global__ void __launch_bounds__(256)
k_wt(const float* __restrict__ w1, const float* __restrict__ w2,
     const float* __restrict__ w3, float* __restrict__ wt) {
    int i = blockIdx.x * 256 + threadIdx.x;   // 0..9919
    if (i < 1728) {                            // w1T: 27x64
        const int k = i >> 6, n = i & 63;
        wt[i] = w1[n * 27 + k];
    } else if (i < 1728 + 4096) {              // w2T
        const int j = i - 1728, k = j >> 6, n = j & 63;
        wt[i] = w2[n * 64 + k];
    } else if (i < 1728 + 8192) {              // w3T
        const int j = i - 5824, k = j >> 6, n = j & 63;
        wt[i] = w3[n * 64 + k];
    }
}

// fp32 corner indices (RGB encode phase only — reads original fp32 rgb table)
__device__ __forceinline__ void corner_indices(int l, float qx, float qy, float qz,
                                               unsigned idx[8],
                                               float& fx, float& fy, float& fz)
{
    const float scale = k_scales[l];
    float px = qx * scale + 0.5f;
    float py = qy * scale + 0.5f;
    float pz = qz * scale + 0.5f;
    float gx = floorf(px), gy = floorf(py), gz = floorf(pz);
    fx = px - gx; fy = py - gy; fz = pz - gz;
    unsigned ix = (unsigned)gx, iy = (unsigned)gy, iz = (unsigned)gz;
    const unsigned off = k_offs[l];
    if (l < 3) {
        const unsigned S  = k_strides[l];
        const unsigned S2 = S * S;
        const unsigned base = off + ix + iy * S + iz * S2;
        idx[0] = base;          idx[1] = base + 1u;
        idx[2] = base + S;      idx[3] = base + S + 1u;
        idx[4] = base + S2;     idx[5] = base + S2 + 1u;
        idx[6] = base + S2 + S; idx[7] = base + S2 + S + 1u;
    } else {
        const unsigned x0 = ix, x1 = ix + 1u;
        const unsigned hy0 = iy * PRIME1, hy1 = hy0 + PRIME1;
        const unsigned hz0 = iz * PRIME2, hz1 = hz0 + PRIME2;
        idx[0] = off + ((x0 ^ hy0 ^ hz0) & HMASK);
        idx[1] = off + ((x1 ^ hy0 ^ hz0) & HMASK);
        idx[2] = off + ((x0 ^ hy1 ^ hz0) & HMASK);
        idx[3] = off + ((x1 ^ hy1 ^ hz0) & HMASK);
        idx[4] = off + ((x0 ^ hy0 ^ hz1) & HMASK);
        idx[5] = off + ((x1 ^ hy0 ^ hz1) & HMASK);
        idx[6] = off + ((x0 ^ hy1 ^ hz1) & HMASK);
        idx[7] = off + ((x1 ^ hy1 ^ hz1) & HMASK);
    }
}

extern "C" __global__ void __launch_bounds__(256, 4)
fused_nerf(const float4* __restrict__ x4,
           const unsigned* __restrict__ W,     // rebuilt fp16 label table
           const float*   __restrict__ wt,     // [w1T 1728 | w2T 4096 | w3T 4096]
           const float4*  __restrict__ tr,
           const float*   __restrict__ wl,
           const float*   __restrict__ bl,
           const float*   __restrict__ b1,
           const float*   __restrict__ b2,
           const float*   __restrict__ b3,
           const float*   __restrict__ w4, const float* __restrict__ b4,
           float* __restrict__ o_hits,
           float* __restrict__ o_sig,
           float* __restrict__ o_idx,
           float* __restrict__ o_rgb)
{
    const int tid = threadIdx.x;
    const int ray0 = blockIdx.x * RPB;

    __shared__ float s_sig[PPB];       // 6400 B
    __shared__ float s_geom[RPB * 8];  // 256 B
    __shared__ float s_h0[RPB * 28];   // 896 B
    __shared__ float s_hA[RPB * 64];   // 2048 B
    __shared__ float s_hB[RPB * 64];   // 2048 B
    __shared__ int   s_fi[RPB];        // 32 B

    // ---- phase 0: per-ray geometry ----
    if (tid < RPB) {
        const float4 ang = x4[ray0 + tid];
        float st1, ct1, sp1, cp1, st2, ct2, sp2, cp2;
        sincosf(ang.x, &st1, &ct1);
        sincosf(ang.y, &sp1, &cp1);
        sincosf(ang.z, &st2, &ct2);
        sincosf(ang.w, &sp2, &cp2);
        const float p1x = st1 * cp1, p1y = st1 * sp1, p1z = ct1;
        const float p2x = st2 * cp2, p2y = st2 * sp2, p2z = ct2;
        const float dx = p2x - p1x, dy = p2y - p1y, dz = p2z - p1z;
        float len = sqrtf(dx * dx + dy * dy + dz * dz);
        len = fminf(fmaxf(len, 1e-6f), 1e6f);
        float* g = &s_geom[tid * 8];
        g[0] = p1x; g[1] = p1y; g[2] = p1z; g[3] = len;
        g[4] = dx;  g[5] = dy;  g[6] = dz;  g[7] = 0.f;
    }
    __syncthreads();

    // ---- phase 1: label encode + sigmoid for 1600 points ----
    const size_t sig_base = (size_t)blockIdx.x * PPB;
    auto process = [&](int p) {
        const int r = (p * 5243) >> 20;      // p / 200 for p < 3200
        const int t = p - r * 200;
        const float* g = &s_geom[r * 8];
        const float tt = (float)t * (1.0f / 199.0f);
        const float qx = ((g[0] + g[4] * tt) + 1.0f) * 0.5f;
        const float qy = ((g[1] + g[5] * tt) + 1.0f) * 0.5f;
        const float qz = ((g[2] + g[6] * tt) + 1.0f) * 0.5f;

        float feat[6];
        #pragma unroll
        for (int l = 0; l < 6; ++l) {
            const float scale = k_scales[l];
            float px = qx * scale + 0.5f;
            float py = qy * scale + 0.5f;
            float pz = qz * scale + 0.5f;
            float gx = floorf(px), gy = floorf(py), gz = floorf(pz);
            const float fx = px - gx, fy = py - gy, fz = pz - gz;
            const unsigned ix = (unsigned)gx, iy = (unsigned)gy, iz = (unsigned)gz;
            const float wx0 = 1.0f - fx, wx1 = fx;
            const float wyz[4] = { (1.0f - fy) * (1.0f - fz), fy * (1.0f - fz),
                                   (1.0f - fy) * fz,          fy * fz };
            float acc = 0.0f;
            if (l < 3) {
                const unsigned S  = k_strides[l];
                const unsigned S2 = S * S;
                const unsigned base = k_offs[l] + ix + iy * S + iz * S2;
                const float2 c0 = up2(W[base]);
                const float2 c1 = up2(W[base + S]);
                const float2 c2 = up2(W[base + S2]);
                const float2 c3 = up2(W[base + S2 + S]);
                acc = fmaf(wx0 * wyz[0], c0.x, acc);
                acc = fmaf(wx1 * wyz[0], c0.y, acc);
                acc = fmaf(wx0 * wyz[1], c1.x, acc);
                acc = fmaf(wx1 * wyz[1], c1.y, acc);
                acc = fmaf(wx0 * wyz[2], c2.x, acc);
                acc = fmaf(wx1 * wyz[2], c2.y, acc);
                acc = fmaf(wx0 * wyz[3], c3.x, acc);
                acc = fmaf(wx1 * wyz[3], c3.y, acc);
            } else {
                const unsigned h32 = k_h32[l - 3];
                const unsigned hy0 = iy * PRIME1, hy1 = hy0 + PRIME1;
                const unsigned hz0 = iz * PRIME2, hz1 = hz0 + PRIME2;
                const unsigned x1 = ix + 1u;
                const unsigned e[4] = { hy0 ^ hz0, hy1 ^ hz0, hy0 ^ hz1, hy1 ^ hz1 };
                #pragma unroll
                for (int j = 0; j < 4; ++j) {
                    const unsigned a = (ix ^ e[j]) & HMASK;
                    const unsigned b = (x1 ^ e[j]) & HMASK;
                    const unsigned wa = a >> 1, wb = b >> 1;
                    const unsigned pa = W[h32 + wa];
                    const float v0 = h2f_sel(pa, a & 1u);
                    float v1;
                    if (wb == wa) {
                        v1 = h2f_sel(pa, b & 1u);     // same word, free
                    } else {
                        v1 = h2f_sel(W[h32 + wb], b & 1u);
                    }
                    acc = fmaf(wx0 * wyz[j], v0, acc);
                    acc = fmaf(wx1 * wyz[j], v1, acc);
                }
            }
            feat[l] = acc;
        }
        float z = bl[0];
        #pragma unroll
        for (int l = 0; l < 6; ++l) z = fmaf(feat[l], wl[l], z);
        const float out = 1.0f / (1.0f + __expf(-z));
        o_sig[sig_base + p] = out;
        s_sig[p] = out;
    };

    #pragma unroll 1
    for (int k = 0; k < 3; ++k) {
        const int p0 = tid + k * 512;
        process(p0);          // two independent points in flight
        process(p0 + 256);
    }
    if (tid < 64) process(1536 + tid);
    __syncthreads();

    // ---- phase 2: per-ray max + first-hit (32 threads per ray) ----
    {
        const int g = tid >> 5, l = tid & 31;
        float vmax = -1.0f;
        int fh = 0x7fff;
        #pragma unroll
        for (int j = 0; j < 7; ++j) {
            const int t = l + j * 32;
            if (t < 200) {
                const float v = s_sig[g * 200 + t];
                vmax = fmaxf(vmax, v);
                if (v > 0.5f) fh = min(fh, t);
            }
        }
        #pragma unroll
        for (int m = 16; m >= 1; m >>= 1) {
            vmax = fmaxf(vmax, __shfl_xor(vmax, m, 64));
            fh = min(fh, __shfl_xor(fh, m, 64));
        }
        if (l == 0) {
            o_hits[ray0 + g] = vmax;
            const int fi = (fh == 0x7fff) ? 0 : fh;
            s_fi[g] = fi;
            o_idx[ray0 + g] = (float)fi;
        }
    }
    __syncthreads();

    // ---- phase 3: dirs + RGB encode at hit points ----
    if (tid < RPB) {
        const float* g = &s_geom[tid * 8];
        const float inv = 1.0f / g[3];
        s_h0[tid * 28 + 0] = g[4] * inv;
        s_h0[tid * 28 + 1] = g[5] * inv;
        s_h0[tid * 28 + 2] = g[6] * inv;
        s_h0[tid * 28 + 27] = 0.f;
    }
    if (tid < RPB * 6) {
        const int r = (tid * 171) >> 10;   // tid / 6
        const int l = tid - r * 6;
        const float* g = &s_geom[r * 8];
        const float t  = (float)s_fi[r] * (1.0f / 199.0f);
        const float qx = ((g[0] + g[4] * t) + 1.0f) * 0.5f;
        const float qy = ((g[1] + g[5] * t) + 1.0f) * 0.5f;
        const float qz = ((g[2] + g[6] * t) + 1.0f) * 0.5f;
        unsigned idx[8];
        float fx, fy, fz;
        corner_indices(l, qx, qy, qz, idx, fx, fy, fz);
        const float ex = 1.0f - fx, ey = 1.0f - fy, ez = 1.0f - fz;
        const float w[8] = { ex * ey * ez, fx * ey * ez, ex * fy * ez, fx * fy * ez,
                             ex * ey * fz, fx * ey * fz, ex * fy * fz, fx * fy * fz };
        float ax = 0.f, ay = 0.f, az = 0.f, aw = 0.f;
        #pragma unroll
        for (int c = 0; c < 8; ++c) {
            float4 v = tr[idx[c]];
            ax = fmaf(w[c], v.x, ax);
            ay = fmaf(w[c], v.y, ay);
            az = fmaf(w[c], v.z, az);
            aw = fmaf(w[c], v.w, aw);
        }
        float* h = &s_h0[r * 28 + 3 + l * 4];
        h[0] = ax; h[1] = ay; h[2] = az; h[3] = aw;
    }
    __syncthreads();

    // ---- phase 4: MLP (weights from global, transposed & cache-resident) ----
    const int n = tid & 63;
    const int wv = tid >> 6;
    const float* w1T = wt;
    const float* w2T = wt + 1728;
    const float* w3T = wt + 5824;
    {
        float a0 = b1[n], a1 = a0;
        #pragma unroll
        for (int k = 0; k < 27; ++k) {
            const float w = w1T[k * 64 + n];
            a0 = fmaf(s_h0[(wv    ) * 28 + k], w, a0);
            a1 = fmaf(s_h0[(wv + 4) * 28 + k], w, a1);
        }
        s_hA[(wv    ) * 64 + n] = fmaxf(a0, 0.0f);
        s_hA[(wv + 4) * 64 + n] = fmaxf(a1, 0.0f);
    }
    __syncthreads();
    {
        float a0 = b2[n], a1 = a0;
        #pragma unroll
        for (int k = 0; k < 64; ++k) {
            const float w = w2T[k * 64 + n];
            a0 = fmaf(s_hA[(wv    ) * 64 + k], w, a0);
            a1 = fmaf(s_hA[(wv + 4) * 64 + k], w, a1);
        }
        s_hB[(wv    ) * 64 + n] = fmaxf(a0, 0.0f);
        s_hB[(wv + 4) * 64 + n] = fmaxf(a1, 0.0f);
    }
    __syncthreads();
    {
        float a0 = b3[n], a1 = a0;
        #pragma unroll
        for (int k = 0; k < 64; ++k) {
            const float w = w3T[k * 64 + n];
            a0 = fmaf(s_hB[(wv    ) * 64 + k], w, a0);
            a1 = fmaf(s_hB[(wv + 4) * 64 + k], w, a1);
        }
        s_hA[(wv    ) * 64 + n] = fmaxf(a0, 0.0f);
        s_hA[(wv + 4) * 64 + n] = fmaxf(a1, 0.0f);
    }
    __syncthreads();
    if (tid < RPB * 3) {
        const int r = (tid * 86) >> 8;     // tid / 3
        const int c = tid - r * 3;
        float acc = b4[c];
        #pragma unroll
        for (int k = 0; k < 64; ++k) acc = fmaf(s_hA[r * 64 + k], w4[c * 64 + k], acc);
        o_rgb[(ray0 + r) * 3 + c] = acc;
    }
}

extern "C" void kernel_launch(void* const* d_in, const int* in_sizes, int n_in,
                              void* d_out, int out_size, void* d_ws, size_t ws_size,
                              hipStream_t stream) {
    const float* x  = (const float*)d_in[0];
    const float* tl = (const float*)d_in[1];
    const float* tr = (const float*)d_in[2];
    const float* wl = (const float*)d_in[3];
    const float* bl = (const float*)d_in[4];
    const float* w1 = (const float*)d_in[5];
    const float* b1 = (const float*)d_in[6];
    const float* w2 = (const float*)d_in[7];
    const float* b2 = (const float*)d_in[8];
    const float* w3 = (const float*)d_in[9];
    const float* b3 = (const float*)d_in[10];
    const float* w4 = (const float*)d_in[11];
    const float* b4 = (const float*)d_in[12];

    float* o      = (float*)d_out;
    float* o_hits = o;
    float* o_sig  = o + NRAYS;
    float* o_idx  = o_sig + (size_t)NRAYS * NPTS;
    float* o_rgb  = o_idx + NRAYS;

    // ws layout: [ u32 table: 4,407,712 B | pad to 4,407,808 | wT: 9920 floats ]
    unsigned* W  = (unsigned*)d_ws;
    float*    wt = (float*)((char*)d_ws + 4407808);

    k_build<<<dim3((W_U32 + 255) / 256), dim3(256), 0, stream>>>(tl, W);
    k_wt<<<dim3((9920 + 255) / 256), dim3(256), 0, stream>>>(w1, w2, w3, wt);
    fused_nerf<<<dim3(NRAYS / RPB), dim3(256), 0, stream>>>(
        (const float4*)x, W, wt, (const float4*)tr, wl, bl,
        b1, b2, b3, w4, b4,
        o_hits, o_sig, o_idx, o_rgb);
}